// Round 18
// baseline (577.276 us; speedup 1.0000x reference)
//
#include <hip/hip_runtime.h>
#include <math.h>

typedef __attribute__((ext_vector_type(8))) short bf16x8;
typedef __attribute__((ext_vector_type(4))) float f32x4;
typedef unsigned short u16;

__device__ __forceinline__ short f2bf(float x) {
  union { float f; unsigned u; } c; c.f = x;
  unsigned u = c.u;
  u += 0x7fffu + ((u >> 16) & 1u);
  return (short)(u >> 16);
}
__device__ __forceinline__ float bf2f(u16 b) {
  union { unsigned u; float f; } c; c.u = ((unsigned)b) << 16; return c.f;
}
__device__ __forceinline__ unsigned pack2(float a, float b) {
  return ((unsigned)(u16)f2bf(a)) | (((unsigned)(u16)f2bf(b)) << 16);
}
__device__ __forceinline__ unsigned cvtpk(float lo, float hi) {
  unsigned r;
  asm("v_cvt_pk_bf16_f32 %0, %1, %2" : "=v"(r) : "v"(lo), "v"(hi));
  return r;
}
__device__ __forceinline__ u16 f2bf1(float x) {   // single-op bf16 convert
  return (u16)cvtpk(x, x);
}
__device__ __forceinline__ float bfu_lo(unsigned v) {
  union { unsigned u; float f; } c; c.u = v << 16; return c.f;
}
__device__ __forceinline__ float bfu_hi(unsigned v) {
  union { unsigned u; float f; } c; c.u = v & 0xffff0000u; return c.f;
}
// A&S 7.1.25: no exp, max err ~5e-4 (<< bf16 eps)
__device__ __forceinline__ float fast_erf(float x) {
  float ax = fabsf(x);
  float p = 1.f + ax * (0.278393f + ax * (0.230389f + ax * (0.000972f + ax * 0.078108f)));
  p = p * p; p = p * p;
  float y = 1.f - __frcp_rn(p);
  return copysignf(y, x);
}
__device__ __forceinline__ float gelu1(float x) {
  return 0.5f * x * (1.0f + fast_erf(x * 0.70710678118654752f));
}
__device__ __forceinline__ void gload16(const void* g, void* l) {
  __builtin_amdgcn_global_load_lds(
      (const __attribute__((address_space(1))) void*)g,
      (__attribute__((address_space(3))) void*)l, 16, 0, 0);
}

// ---------------- index handling ----------------
__global__ void detect_kernel(const unsigned* __restrict__ idx32, int* __restrict__ flag) {
  __shared__ int anyNZ;
  if (threadIdx.x == 0) anyNZ = 0;
  __syncthreads();
  unsigned v = idx32[threadIdx.x * 2 + 1];
  if (v != 0u) atomicOr(&anyNZ, 1);
  __syncthreads();
  if (threadIdx.x == 0) *flag = (anyNZ == 0) ? 1 : 0;  // 1 => int64 input
}

// convert idx to int32 AND count src occurrences (cnt pre-zeroed)
__global__ void convert_count_kernel(const void* __restrict__ in, int* __restrict__ s32,
                                     const int* __restrict__ flag, int* __restrict__ cnt,
                                     int E) {
  int i = blockIdx.x * 256 + threadIdx.x;
  if (i >= 2 * E) return;
  int f = *flag;
  int v = f ? (int)((const long long*)in)[i] : ((const int*)in)[i];
  s32[i] = v;
  if (i < E) atomicAdd(&cnt[v], 1);
}

__global__ void __launch_bounds__(1024)
scan_kernel(const int* __restrict__ cnt, int* __restrict__ offs, int n) {
  __shared__ int sp[1024];
  int t = threadIdx.x;
  int chunk = (n + 1023) / 1024;
  int begin = t * chunk;
  int end = begin + chunk; if (end > n) end = n; if (begin > n) begin = n;
  int s = 0;
  for (int i = begin; i < end; ++i) s += cnt[i];
  sp[t] = s;
  __syncthreads();
  for (int o = 1; o < 1024; o <<= 1) {
    int v = (t >= o) ? sp[t - o] : 0;
    __syncthreads();
    sp[t] += v;
    __syncthreads();
  }
  int run = (t == 0) ? 0 : sp[t - 1];
  for (int i = begin; i < end; ++i) { offs[i] = run; run += cnt[i]; }
  if (t == 0) offs[n] = sp[1023];
}

// order[p] = original edge index at CSR position p
__global__ void scatter_kernel(const int* __restrict__ src, const int* __restrict__ offs,
                               int* __restrict__ cur, int* __restrict__ order, int E) {
  int i = blockIdx.x * 256 + threadIdx.x;
  if (i >= E) return;
  int s = src[i];
  int p = offs[s] + atomicAdd(&cur[s], 1);
  order[p] = i;
}

// ---------------- weight fp32 -> bf16 ----------------
// layout: W1[49152] | W2[16384] | W3[512] | Wv[16384] | Wo[16384] | Wg[16384]
// W1/W2/Wv are CHUNK-SWIZZLED for LDS staging: chunk c (32 K-cols) stored as
//   chunkBase + row*32 + ((s ^ ((row>>1)&3))<<3) + e   (s = (k%32)/8, e = k%8)
__global__ void wcvt_kernel(const float* __restrict__ B1, const float* __restrict__ B2,
                            const float* __restrict__ B3, const float* __restrict__ Wv,
                            const float* __restrict__ Wo, const float* __restrict__ Wg,
                            short* __restrict__ o) {
  int i = blockIdx.x * 256 + threadIdx.x;
  if (i >= 115200) return;
  float val; int dst;
  if (i < 49152) {
    int row = i / 384, k = i % 384;
    val = B1[i];
    int c = k >> 5, s = (k >> 3) & 3, e = k & 7;
    dst = c * 4096 + row * 32 + ((s ^ ((row >> 1) & 3)) << 3) + e;
  } else if (i < 65536) {
    int j = i - 49152; int row = j >> 7, k = j & 127;
    val = B2[j];
    int c = k >> 5, s = (k >> 3) & 3, e = k & 7;
    dst = 49152 + c * 4096 + row * 32 + ((s ^ ((row >> 1) & 3)) << 3) + e;
  } else if (i < 66048) { val = B3[i - 65536]; dst = i; }
  else if (i < 82432) {
    int j = i - 66048; int row = j >> 7, k = j & 127;
    val = Wv[j];
    int c = k >> 5, s = (k >> 3) & 3, e = k & 7;
    dst = 66048 + c * 4096 + row * 32 + ((s ^ ((row >> 1) & 3)) << 3) + e;
  }
  else if (i < 98816)  { val = Wo[i - 82432]; dst = i; }
  else                 { val = Wg[i - 98816]; dst = i; }
  o[dst] = f2bf(val);
}

// ---------------- fp32 -> bf16 bulk convert (hV only, 5 MB) ----------------
__global__ void cvtbf_kernel(const float* __restrict__ in, u16* __restrict__ out, long n8) {
  long i = (long)blockIdx.x * blockDim.x + threadIdx.x;
  long stride = (long)gridDim.x * blockDim.x;
  for (; i < n8; i += stride) {
    long b = i * 8;
    float4 a = *(const float4*)(in + b);
    float4 c = *(const float4*)(in + b + 4);
    uint4 u;
    u.x = pack2(a.x, a.y); u.y = pack2(a.z, a.w);
    u.z = pack2(c.x, c.y); u.w = pack2(c.z, c.w);
    *(uint4*)(out + b) = u;
  }
}

// ---------------- edge kernel: R17 engine, TE=128, 53KB LDS, 3 blocks/CU ---
// 128 edges/block, 4 waves (2x2 of 64x64 tiles). 20 drain-per-step chunk-steps
// with 16 MFMA each (per-edge barrier overhead halved vs TE=64).
__global__ void __launch_bounds__(256, 3)
edge_kernel(const u16* __restrict__ hVb, const float* __restrict__ hE,
            const int* __restrict__ src, const int* __restrict__ dst,
            u16* __restrict__ Vout,
            const short* __restrict__ W1, const float* __restrict__ b1,
            const short* __restrict__ W2, const float* __restrict__ b2,
            const short* __restrict__ W3b, const float* __restrict__ b3,
            const short* __restrict__ Wv, const float* __restrict__ bv,
            float* __restrict__ logits, int E) {
  __shared__ u16 sEH[128 * 128];      // 32KB: hE -> H -> V-bounce
  __shared__ u16 sW[2][4096];         // 16KB weight chunk double-buffer
  __shared__ float sPart[128][4][2];  // 4KB

  const int t = threadIdx.x;
  const int eBase = blockIdx.x * 128;
  const int lane = t & 63;
  const int wid = t >> 6;
  const int wrow = (wid >> 1) * 64;
  const int wcol = (wid & 1) * 64;
  const int lrow = lane & 15;
  const int kgrp = lane >> 4;

  auto STAGE = [&](const short* cp, int buf) {
#pragma unroll
    for (int i = 0; i < 2; ++i) {
      int L = t + i * 256;
      gload16(cp + L * 8, &sW[buf][L * 8]);
    }
  };

  // ---- prologue: stage Wv chunk 0 (async), then hE staging ----
  STAGE(Wv, 0);

  // stage hE (fp32 contiguous) -> sEH bf16, swizzled
#pragma unroll
  for (int i = 0; i < 8; ++i) {
    int u = t + i * 256;             // 0..2047 8-float units
    int row = u >> 4, sg = u & 15;
    const float* p = hE + (size_t)min(eBase + row, E - 1) * 128 + sg * 8;
    float4 f0 = *(const float4*)p;
    float4 f1 = *(const float4*)(p + 4);
    uint4 cv;
    cv.x = cvtpk(f0.x, f0.y); cv.y = cvtpk(f0.z, f0.w);
    cv.z = cvtpk(f1.x, f1.y); cv.w = cvtpk(f1.z, f1.w);
    *(uint4*)&sEH[row * 128 + ((sg ^ (row & 15)) * 8)] = cv;
  }

  // indices only (fragments loaded inline at use)
  int rS[4], rD[4];
#pragma unroll
  for (int mi = 0; mi < 4; ++mi) {
    int e = min(eBase + wrow + mi * 16 + lrow, E - 1);
    rS[mi] = src[e];
    rD[mi] = dst[e];
  }
  asm volatile("s_waitcnt vmcnt(0)" ::: "memory");
  __syncthreads();

  f32x4 acc[4][4];
  auto ZACC = [&]() {
#pragma unroll
    for (int mi = 0; mi < 4; ++mi)
#pragma unroll
      for (int nf = 0; nf < 4; ++nf)
#pragma unroll
        for (int q = 0; q < 4; ++q) acc[mi][nf][q] = 0.f;
  };
  auto LDSA = [&](int kk, bf16x8* a) {
#pragma unroll
    for (int mi = 0; mi < 4; ++mi) {
      int row = wrow + mi * 16 + lrow;
      int seg = (kk >> 3) ^ (row & 15);
      a[mi] = *(const bf16x8*)&sEH[row * 128 + seg * 8];
    }
  };
  // one pipelined chunk-step (R10/R17 engine, 16 MFMA)
  auto STEP = [&](int buf, const short* nextCp, const bf16x8* a) {
    if (nextCp) STAGE(nextCp, buf ^ 1);
    bf16x8 b[4];
#pragma unroll
    for (int nf = 0; nf < 4; ++nf) {
      int row = wcol + nf * 16 + lrow;
      int seg = kgrp ^ ((row >> 1) & 3);
      b[nf] = *(const bf16x8*)&sW[buf][row * 32 + seg * 8];
    }
#pragma unroll
    for (int nf = 0; nf < 4; ++nf)
#pragma unroll
      for (int mi = 0; mi < 4; ++mi)
        acc[mi][nf] = __builtin_amdgcn_mfma_f32_16x16x32_bf16(a[mi], b[nf], acc[mi][nf], 0, 0, 0);
    if (nextCp) asm volatile("s_waitcnt vmcnt(0)" ::: "memory");
    __syncthreads();
  };
  // same step but A gathered inline from hVb (drained by the step's vmcnt(0))
  auto STEPG = [&](int buf, const short* nextCp, const int* r, int c4) {
    bf16x8 a[4];
    const int kk = c4 * 32 + kgrp * 8;
#pragma unroll
    for (int mi = 0; mi < 4; ++mi)
      a[mi] = *(const bf16x8*)(hVb + (size_t)r[mi] * 128 + kk);
    STEP(buf, nextCp, a);
  };

  // ---------------- V phase: Wv chunks 0..3 x sEH(hE) ----------------
  ZACC();
#pragma unroll
  for (int c = 0; c < 4; ++c) {
    bf16x8 a[4];
    LDSA(c * 32 + kgrp * 8, a);
    const short* nxt = (c < 3) ? (Wv + (c + 1) * 4096) : (W1 + 4 * 4096);
    STEP(c & 1, nxt, a);
  }
  // defer V output: pack (acc + bv) to bf16 pairs (32 VGPRs)
  unsigned vpk[4][4][2];
  {
    float bvc[4];
#pragma unroll
    for (int nf = 0; nf < 4; ++nf) bvc[nf] = bv[wcol + nf * 16 + lrow];
#pragma unroll
    for (int mi = 0; mi < 4; ++mi)
#pragma unroll
      for (int nf = 0; nf < 4; ++nf) {
        vpk[mi][nf][0] = cvtpk(acc[mi][nf][0] + bvc[nf], acc[mi][nf][1] + bvc[nf]);
        vpk[mi][nf][1] = cvtpk(acc[mi][nf][2] + bvc[nf], acc[mi][nf][3] + bvc[nf]);
      }
  }

  // ---------------- layer 1: hE section (W1 c4..c7), aS (c0..c3), aD (c8..c11)
  ZACC();
#pragma unroll
  for (int c = 0; c < 4; ++c) {
    bf16x8 a[4];
    LDSA(c * 32 + kgrp * 8, a);
    const short* nxt = (c < 3) ? (W1 + (5 + c) * 4096) : W1;
    STEP(c & 1, nxt, a);
  }
  STEPG(0, W1 + 1 * 4096, rS, 0);
  STEPG(1, W1 + 2 * 4096, rS, 1);
  STEPG(0, W1 + 3 * 4096, rS, 2);
  STEPG(1, W1 + 8 * 4096, rS, 3);
  STEPG(0, W1 + 9 * 4096, rD, 0);
  STEPG(1, W1 + 10 * 4096, rD, 1);
  STEPG(0, W1 + 11 * 4096, rD, 2);
  STEPG(1, W2, rD, 3);

  // ---- L1 epilogue: sEH = relu(acc + b1) (hE dead after c4..c7) ----
  {
    float b1c[4];
#pragma unroll
    for (int nf = 0; nf < 4; ++nf) b1c[nf] = b1[wcol + nf * 16 + lrow];
#pragma unroll
    for (int mi = 0; mi < 4; ++mi)
#pragma unroll
      for (int nf = 0; nf < 4; ++nf)
#pragma unroll
        for (int q = 0; q < 4; ++q) {
          int row = wrow + mi * 16 + kgrp * 4 + q;
          int col = wcol + nf * 16 + lrow;
          int seg = (col >> 3) ^ (row & 15);
          sEH[row * 128 + seg * 8 + (col & 7)] =
              f2bf1(fmaxf(acc[mi][nf][q] + b1c[nf], 0.f));
        }
  }
  __syncthreads();

  // ---------------- layer 2: W2 chunks 0..3 x sEH(H) ----------------
  ZACC();
#pragma unroll
  for (int c = 0; c < 4; ++c) {
    bf16x8 a[4];
    LDSA(c * 32 + kgrp * 8, a);
    const short* nxt = (c < 3) ? (W2 + (c + 1) * 4096) : nullptr;
    STEP(c & 1, nxt, a);
  }
  // ---- L2 epilogue (+ folded layer 3) ----
  {
    float b2c[4], w3v[4][4];
#pragma unroll
    for (int nf = 0; nf < 4; ++nf) {
      int col = wcol + nf * 16 + lrow;
      b2c[nf] = b2[col];
#pragma unroll
      for (int h = 0; h < 4; ++h) w3v[h][nf] = bf2f((u16)W3b[h * 128 + col]);
    }
#pragma unroll
    for (int mi = 0; mi < 4; ++mi)
#pragma unroll
      for (int q = 0; q < 4; ++q) {
        float p0 = 0.f, p1 = 0.f, p2 = 0.f, p3 = 0.f;
#pragma unroll
        for (int nf = 0; nf < 4; ++nf) {
          float x = fmaxf(acc[mi][nf][q] + b2c[nf], 0.f);
          p0 += x * w3v[0][nf]; p1 += x * w3v[1][nf];
          p2 += x * w3v[2][nf]; p3 += x * w3v[3][nf];
        }
#pragma unroll
        for (int o = 1; o < 16; o <<= 1) {
          p0 += __shfl_xor(p0, o); p1 += __shfl_xor(p1, o);
          p2 += __shfl_xor(p2, o); p3 += __shfl_xor(p3, o);
        }
        if (lrow < 4) {
          float pw = (lrow == 0) ? p0 : (lrow == 1) ? p1 : (lrow == 2) ? p2 : p3;
          sPart[wrow + mi * 16 + kgrp * 4 + q][lrow][wid & 1] = pw;
        }
      }
  }
  __syncthreads();
#pragma unroll
  for (int it = 0; it < 2; ++it) {
    int item = t * 2 + it;           // 0..511
    int r = item >> 2, h = item & 3;
    float lg = (sPart[r][h][0] + sPart[r][h][1] + b3[h]) * 0.17677669529663687f;
    int e = eBase + r;
    if (e < E) logits[(size_t)e * 4 + h] = lg;
  }

  // ---------------- V finale: gelu(vpk) -> sEH (dead) -> coalesced store ----
#pragma unroll
  for (int mi = 0; mi < 4; ++mi)
#pragma unroll
    for (int nf = 0; nf < 4; ++nf)
#pragma unroll
      for (int p = 0; p < 2; ++p) {
        float x0 = bfu_lo(vpk[mi][nf][p]);
        float x1 = bfu_hi(vpk[mi][nf][p]);
        int col = wcol + nf * 16 + lrow;
        int row0 = wrow + mi * 16 + kgrp * 4 + p * 2;
        int seg0 = (col >> 3) ^ (row0 & 15);
        int seg1 = (col >> 3) ^ ((row0 + 1) & 15);
        sEH[row0 * 128 + seg0 * 8 + (col & 7)] = f2bf1(gelu1(x0));
        sEH[(row0 + 1) * 128 + seg1 * 8 + (col & 7)] = f2bf1(gelu1(x1));
      }
  __syncthreads();
#pragma unroll
  for (int i = 0; i < 8; ++i) {
    int u = t + i * 256;             // 0..2047 16B-lines
    int row = u >> 4, g16 = u & 15;
    int seg = g16 ^ (row & 15);
    uint4 v = *(const uint4*)&sEH[row * 128 + seg * 8];
    int e = eBase + row;
    if (e < E) *(uint4*)(Vout + (size_t)e * 128 + g16 * 8) = v;
  }
}

__device__ __forceinline__ float dot8(const float* ag, uint4 w) {
  unsigned wr[4] = {w.x, w.y, w.z, w.w};
  float s = 0.f;
#pragma unroll
  for (int q = 0; q < 4; ++q) {
    s += ag[2 * q]     * bf2f((u16)(wr[q] & 0xffffu));
    s += ag[2 * q + 1] * bf2f((u16)(wr[q] >> 16));
  }
  return s;
}

// ---------------- FUSED node kernel: softmax + aggregation + GEMV ----------
// one node per WAVE; lane = 16 dim-groups x 4 edge-slots. Pass 1 computes the
// per-head max inline; pass 2 computes exp weights, denominator, and the
// weighted-V accumulation; xor-16/32 reduction covers all 4 edge stripes.
__global__ void __launch_bounds__(256, 2)
agg_kernel(const float* __restrict__ hV, const float* __restrict__ logits,
           const u16* __restrict__ V,
           const int* __restrict__ offs, const int* __restrict__ order,
           const short* __restrict__ Wob, const short* __restrict__ Wgb,
           const float* __restrict__ gb, float* __restrict__ out, int nN) {
  __shared__ u16 sW[2][16384];      // 64KB
  __shared__ float sAgg[4][132];
  const int t = threadIdx.x;
#pragma unroll
  for (int i = 0; i < 8; ++i) {
    int idx = t + i * 256;          // 0..2047 uint4 per matrix
    int row = idx >> 4, k16 = idx & 15;
    int di = row * 128 + ((k16 ^ (row & 15)) * 8);
    *(uint4*)&sW[0][di] = ((const uint4*)Wob)[idx];
    *(uint4*)&sW[1][di] = ((const uint4*)Wgb)[idx];
  }
  __syncthreads();
  const int wid = t >> 6, lane = t & 63;
  const int dgrp = lane & 15, egrp = lane >> 4, h = dgrp >> 2;
  const int j0 = lane, j1 = lane + 64;
  const int s0 = (j0 & 15), s1 = (j1 & 15);
  for (int v = blockIdx.x * 4 + wid; v < nN; v += gridDim.x * 4) {
    const int base = offs[v], deg = offs[v + 1] - base;
    // pass 1: per-head max (lane's stripe; xor16/32 joins all stripes)
    float m = -3e38f;
    for (int i = egrp; i < deg; i += 4) {
      int e = order[base + i];
      m = fmaxf(m, logits[(size_t)e * 4 + h]);
    }
    m = fmaxf(m, __shfl_xor(m, 16));
    m = fmaxf(m, __shfl_xor(m, 32));
    // pass 2: exp weights + denominator + weighted V accumulation
    float a[8];
#pragma unroll
    for (int q = 0; q < 8; ++q) a[q] = 0.f;
    float dsum = 0.f;
    for (int i = egrp; i < deg; i += 4) {
      int e = order[base + i];
      float w = __expf(logits[(size_t)e * 4 + h] - m);
      dsum += w;
      bf16x8 vv = *(const bf16x8*)(V + (size_t)e * 128 + dgrp * 8);
#pragma unroll
      for (int q = 0; q < 8; ++q) a[q] += w * bf2f((u16)vv[q]);
    }
#pragma unroll
    for (int q = 0; q < 8; ++q) {
      a[q] += __shfl_xor(a[q], 16);
      a[q] += __shfl_xor(a[q], 32);
    }
    dsum += __shfl_xor(dsum, 16);
    dsum += __shfl_xor(dsum, 32);
    float innv = (dsum > 0.f) ? __frcp_rn(dsum) : 0.f;
    if (egrp == 0) {
#pragma unroll
      for (int q = 0; q < 8; ++q) sAgg[wid][dgrp * 8 + q] = a[q] * innv;
    }
    asm volatile("s_waitcnt lgkmcnt(0)" ::: "memory");
    __builtin_amdgcn_wave_barrier();
    float o0 = 0.f, o1 = 0.f, g0 = 0.f, g1 = 0.f;
#pragma unroll 4
    for (int k = 0; k < 128; k += 8) {
      float a8[8];
#pragma unroll
      for (int q = 0; q < 8; ++q) a8[q] = sAgg[wid][k + q];
      int k16 = k >> 3;
      uint4 wo0 = *(const uint4*)&sW[0][j0 * 128 + ((k16 ^ s0) * 8)];
      uint4 wo1 = *(const uint4*)&sW[0][j1 * 128 + ((k16 ^ s1) * 8)];
      uint4 wg0 = *(const uint4*)&sW[1][j0 * 128 + ((k16 ^ s0) * 8)];
      uint4 wg1 = *(const uint4*)&sW[1][j1 * 128 + ((k16 ^ s1) * 8)];
      o0 += dot8(a8, wo0); o1 += dot8(a8, wo1);
      g0 += dot8(a8, wg0); g1 += dot8(a8, wg1);
    }
    float gg0 = 1.f / (1.f + __expf(-(g0 + gb[j0])));
    float gg1 = 1.f / (1.f + __expf(-(g1 + gb[j1])));
    out[(size_t)v * 128 + j0] = hV[(size_t)v * 128 + j0] + o0 * gg0;
    out[(size_t)v * 128 + j1] = hV[(size_t)v * 128 + j1] + o1 * gg1;
    asm volatile("s_waitcnt lgkmcnt(0)" ::: "memory");
    __builtin_amdgcn_wave_barrier();
  }
}

// ---------------- fallback (ws too small marker) ----------------
__global__ void fb_kernel(const float* __restrict__ hV, float* __restrict__ out, int n) {
  int i = blockIdx.x * 256 + threadIdx.x;
  if (i < n) out[i] = hV[i] + 0.5f;
}

extern "C" void kernel_launch(void* const* d_in, const int* in_sizes, int n_in,
                              void* d_out, int out_size, void* d_ws, size_t ws_size,
                              hipStream_t stream) {
  const float* hV   = (const float*)d_in[0];
  const float* hE   = (const float*)d_in[1];
  const void*  eidx = d_in[2];
  const float* WvW  = (const float*)d_in[3];
  const float* WvB  = (const float*)d_in[4];
  const float* B1w  = (const float*)d_in[5];
  const float* B1b  = (const float*)d_in[6];
  const float* B2w  = (const float*)d_in[7];
  const float* B2b  = (const float*)d_in[8];
  const float* B3w  = (const float*)d_in[9];
  const float* B3b  = (const float*)d_in[10];
  const float* WoW  = (const float*)d_in[11];
  const float* GW   = (const float*)d_in[12];
  const float* GB   = (const float*)d_in[13];

  const int Nn = in_sizes[0] / 128;
  const int E  = in_sizes[1] / 128;
  if (Nn <= 0 || E <= 0) return;

  char* ws = (char*)d_ws;
  size_t off = 0;
  auto alloc = [&](size_t b) { size_t o = off; off += (b + 255) & ~(size_t)255; return o; };
  const size_t o_idx   = alloc((size_t)2 * E * 4);
  const size_t o_cnt   = alloc((size_t)(Nn + 1) * 4);
  const size_t o_offs  = alloc((size_t)(Nn + 1) * 4);
  const size_t o_cur   = alloc((size_t)Nn * 4);
  const size_t o_order = alloc((size_t)E * 4);
  const size_t o_flag  = alloc(256);
  const size_t o_log   = alloc((size_t)E * 16);
  const size_t o_V     = alloc((size_t)E * 256);
  const size_t o_hVb   = alloc((size_t)Nn * 256);
  const size_t o_wbf   = alloc((size_t)115200 * 2);

  if (off > ws_size) {
    fb_kernel<<<(out_size + 255) / 256, 256, 0, stream>>>(hV, (float*)d_out, out_size);
    return;
  }

  int*   idx32  = (int*)(ws + o_idx);
  int*   cnt    = (int*)(ws + o_cnt);
  int*   offsP  = (int*)(ws + o_offs);
  int*   cur    = (int*)(ws + o_cur);
  int*   order  = (int*)(ws + o_order);
  int*   flag   = (int*)(ws + o_flag);
  float* logits = (float*)(ws + o_log);
  u16*   Vb     = (u16*)(ws + o_V);
  u16*   hVb    = (u16*)(ws + o_hVb);
  short* wbf    = (short*)(ws + o_wbf);

  short* W1b = wbf;
  short* W2b = wbf + 49152;
  short* W3b = wbf + 65536;
  short* Wvb = wbf + 66048;
  short* Wob = wbf + 82432;
  short* Wgb = wbf + 98816;

  const int* src = idx32;
  const int* dst = idx32 + E;

  detect_kernel<<<1, 256, 0, stream>>>((const unsigned*)eidx, flag);
  hipMemsetAsync(cnt, 0, (size_t)(Nn + 1) * 4, stream);
  hipMemsetAsync(cur, 0, (size_t)Nn * 4, stream);
  convert_count_kernel<<<(2 * E + 255) / 256, 256, 0, stream>>>(eidx, idx32, flag, cnt, E);
  scan_kernel<<<1, 1024, 0, stream>>>(cnt, offsP, Nn);
  scatter_kernel<<<(E + 255) / 256, 256, 0, stream>>>(src, offsP, cur, order, E);
  wcvt_kernel<<<(115200 + 255) / 256, 256, 0, stream>>>(B1w, B2w, B3w, WvW, WoW, GW, wbf);
  cvtbf_kernel<<<512, 256, 0, stream>>>(hV, hVb, (long)Nn * 16);

  edge_kernel<<<(E + 127) / 128, 256, 0, stream>>>(
      hVb, hE, src, dst, Vb, W1b, B1b, W2b, B2b, W3b, B3b, Wvb, WvB, logits, E);

  agg_kernel<<<512, 256, 0, stream>>>(
      hV, logits, Vb, offsP, order, Wob, Wgb, GB, (float*)d_out, Nn);
}

// Round 19
// 511.607 us; speedup vs baseline: 1.1284x; 1.1284x over previous
//
#include <hip/hip_runtime.h>
#include <math.h>

typedef __attribute__((ext_vector_type(8))) short bf16x8;
typedef __attribute__((ext_vector_type(4))) float f32x4;
typedef unsigned short u16;

__device__ __forceinline__ short f2bf(float x) {
  union { float f; unsigned u; } c; c.f = x;
  unsigned u = c.u;
  u += 0x7fffu + ((u >> 16) & 1u);
  return (short)(u >> 16);
}
__device__ __forceinline__ float bf2f(u16 b) {
  union { unsigned u; float f; } c; c.u = ((unsigned)b) << 16; return c.f;
}
__device__ __forceinline__ unsigned pack2(float a, float b) {
  return ((unsigned)(u16)f2bf(a)) | (((unsigned)(u16)f2bf(b)) << 16);
}
__device__ __forceinline__ unsigned cvtpk(float lo, float hi) {
  unsigned r;
  asm("v_cvt_pk_bf16_f32 %0, %1, %2" : "=v"(r) : "v"(lo), "v"(hi));
  return r;
}
__device__ __forceinline__ u16 f2bf1(float x) {   // single-op bf16 convert
  return (u16)cvtpk(x, x);
}
__device__ __forceinline__ float bfu_lo(unsigned v) {
  union { unsigned u; float f; } c; c.u = v << 16; return c.f;
}
__device__ __forceinline__ float bfu_hi(unsigned v) {
  union { unsigned u; float f; } c; c.u = v & 0xffff0000u; return c.f;
}
// A&S 7.1.25: no exp, max err ~5e-4 (<< bf16 eps)
__device__ __forceinline__ float fast_erf(float x) {
  float ax = fabsf(x);
  float p = 1.f + ax * (0.278393f + ax * (0.230389f + ax * (0.000972f + ax * 0.078108f)));
  p = p * p; p = p * p;
  float y = 1.f - __frcp_rn(p);
  return copysignf(y, x);
}
__device__ __forceinline__ float gelu1(float x) {
  return 0.5f * x * (1.0f + fast_erf(x * 0.70710678118654752f));
}
__device__ __forceinline__ void gload16(const void* g, void* l) {
  __builtin_amdgcn_global_load_lds(
      (const __attribute__((address_space(1))) void*)g,
      (__attribute__((address_space(3))) void*)l, 16, 0, 0);
}

// ---------------- index handling ----------------
__global__ void detect_kernel(const unsigned* __restrict__ idx32, int* __restrict__ flag) {
  __shared__ int anyNZ;
  if (threadIdx.x == 0) anyNZ = 0;
  __syncthreads();
  unsigned v = idx32[threadIdx.x * 2 + 1];
  if (v != 0u) atomicOr(&anyNZ, 1);
  __syncthreads();
  if (threadIdx.x == 0) *flag = (anyNZ == 0) ? 1 : 0;  // 1 => int64 input
}

// convert idx to int32 AND count src occurrences (cnt pre-zeroed)
__global__ void convert_count_kernel(const void* __restrict__ in, int* __restrict__ s32,
                                     const int* __restrict__ flag, int* __restrict__ cnt,
                                     int E) {
  int i = blockIdx.x * 256 + threadIdx.x;
  if (i >= 2 * E) return;
  int f = *flag;
  int v = f ? (int)((const long long*)in)[i] : ((const int*)in)[i];
  s32[i] = v;
  if (i < E) atomicAdd(&cnt[v], 1);
}

__global__ void __launch_bounds__(1024)
scan_kernel(const int* __restrict__ cnt, int* __restrict__ offs, int n) {
  __shared__ int sp[1024];
  int t = threadIdx.x;
  int chunk = (n + 1023) / 1024;
  int begin = t * chunk;
  int end = begin + chunk; if (end > n) end = n; if (begin > n) begin = n;
  int s = 0;
  for (int i = begin; i < end; ++i) s += cnt[i];
  sp[t] = s;
  __syncthreads();
  for (int o = 1; o < 1024; o <<= 1) {
    int v = (t >= o) ? sp[t - o] : 0;
    __syncthreads();
    sp[t] += v;
    __syncthreads();
  }
  int run = (t == 0) ? 0 : sp[t - 1];
  for (int i = begin; i < end; ++i) { offs[i] = run; run += cnt[i]; }
  if (t == 0) offs[n] = sp[1023];
}

// order[p] = original edge index at CSR position p
__global__ void scatter_kernel(const int* __restrict__ src, const int* __restrict__ offs,
                               int* __restrict__ cur, int* __restrict__ order, int E) {
  int i = blockIdx.x * 256 + threadIdx.x;
  if (i >= E) return;
  int s = src[i];
  int p = offs[s] + atomicAdd(&cur[s], 1);
  order[p] = i;
}

// ---------------- weight fp32 -> bf16 ----------------
// layout: W1[49152] | W2[16384] | W3[512] | Wv[16384] | Wo[16384] | Wg[16384]
// W1/W2/Wv are CHUNK-SWIZZLED for LDS staging: chunk c (32 K-cols) stored as
//   chunkBase + row*32 + ((s ^ ((row>>1)&3))<<3) + e   (s = (k%32)/8, e = k%8)
__global__ void wcvt_kernel(const float* __restrict__ B1, const float* __restrict__ B2,
                            const float* __restrict__ B3, const float* __restrict__ Wv,
                            const float* __restrict__ Wo, const float* __restrict__ Wg,
                            short* __restrict__ o) {
  int i = blockIdx.x * 256 + threadIdx.x;
  if (i >= 115200) return;
  float val; int dst;
  if (i < 49152) {
    int row = i / 384, k = i % 384;
    val = B1[i];
    int c = k >> 5, s = (k >> 3) & 3, e = k & 7;
    dst = c * 4096 + row * 32 + ((s ^ ((row >> 1) & 3)) << 3) + e;
  } else if (i < 65536) {
    int j = i - 49152; int row = j >> 7, k = j & 127;
    val = B2[j];
    int c = k >> 5, s = (k >> 3) & 3, e = k & 7;
    dst = 49152 + c * 4096 + row * 32 + ((s ^ ((row >> 1) & 3)) << 3) + e;
  } else if (i < 66048) { val = B3[i - 65536]; dst = i; }
  else if (i < 82432) {
    int j = i - 66048; int row = j >> 7, k = j & 127;
    val = Wv[j];
    int c = k >> 5, s = (k >> 3) & 3, e = k & 7;
    dst = 66048 + c * 4096 + row * 32 + ((s ^ ((row >> 1) & 3)) << 3) + e;
  }
  else if (i < 98816)  { val = Wo[i - 82432]; dst = i; }
  else                 { val = Wg[i - 98816]; dst = i; }
  o[dst] = f2bf(val);
}

// ---------------- fp32 -> bf16 bulk convert (hV only, 5 MB) ----------------
__global__ void cvtbf_kernel(const float* __restrict__ in, u16* __restrict__ out, long n8) {
  long i = (long)blockIdx.x * blockDim.x + threadIdx.x;
  long stride = (long)gridDim.x * blockDim.x;
  for (; i < n8; i += stride) {
    long b = i * 8;
    float4 a = *(const float4*)(in + b);
    float4 c = *(const float4*)(in + b + 4);
    uint4 u;
    u.x = pack2(a.x, a.y); u.y = pack2(a.z, a.w);
    u.z = pack2(c.x, c.y); u.w = pack2(c.z, c.w);
    *(uint4*)(out + b) = u;
  }
}

// ---------------- edge kernel: R10 engine, 34KB LDS, 4 blocks/CU, no spill --
// 64 edges/block, 4 waves (2x2 of 32x64). 20 drain-per-step chunk-steps.
// hV fragments loaded INLINE in their steps (no 64-reg hoist -> no spill);
// V output deferred in 16 packed bf16 VGPRs; sEH: hE -> H -> V-bounce.
__global__ void __launch_bounds__(256, 4)
edge_kernel(const u16* __restrict__ hVb, const float* __restrict__ hE,
            const int* __restrict__ src, const int* __restrict__ dst,
            u16* __restrict__ Vout,
            const short* __restrict__ W1, const float* __restrict__ b1,
            const short* __restrict__ W2, const float* __restrict__ b2,
            const short* __restrict__ W3b, const float* __restrict__ b3,
            const short* __restrict__ Wv, const float* __restrict__ bv,
            float* __restrict__ logits, int E) {
  __shared__ u16 sEH[64 * 128];       // 16KB: hE -> H -> V-bounce
  __shared__ u16 sW[2][4096];         // 16KB weight chunk double-buffer
  __shared__ float sPart[64][4][2];   // 2KB

  const int t = threadIdx.x;
  const int eBase = blockIdx.x * 64;
  const int lane = t & 63;
  const int wid = t >> 6;
  const int wrow = (wid >> 1) * 32;
  const int wcol = (wid & 1) * 64;
  const int lrow = lane & 15;
  const int kgrp = lane >> 4;

  auto STAGE = [&](const short* cp, int buf) {
#pragma unroll
    for (int i = 0; i < 2; ++i) {
      int L = t + i * 256;
      gload16(cp + L * 8, &sW[buf][L * 8]);
    }
  };

  // ---- prologue: stage Wv chunk 0 (async), then hE staging ----
  STAGE(Wv, 0);

  // stage hE (fp32 contiguous) -> sEH bf16, swizzled
#pragma unroll
  for (int i = 0; i < 4; ++i) {
    int u = t + i * 256;             // 0..1023 8-float units
    int row = u >> 4, sg = u & 15;
    const float* p = hE + (size_t)min(eBase + row, E - 1) * 128 + sg * 8;
    float4 f0 = *(const float4*)p;
    float4 f1 = *(const float4*)(p + 4);
    uint4 cv;
    cv.x = cvtpk(f0.x, f0.y); cv.y = cvtpk(f0.z, f0.w);
    cv.z = cvtpk(f1.x, f1.y); cv.w = cvtpk(f1.z, f1.w);
    *(uint4*)&sEH[row * 128 + ((sg ^ (row & 15)) * 8)] = cv;
  }

  // indices only (fragments loaded inline at use)
  int rS[2], rD[2];
#pragma unroll
  for (int mi = 0; mi < 2; ++mi) {
    int e = min(eBase + wrow + mi * 16 + lrow, E - 1);
    rS[mi] = src[e];
    rD[mi] = dst[e];
  }
  asm volatile("s_waitcnt vmcnt(0)" ::: "memory");
  __syncthreads();

  f32x4 acc[2][4];
  auto ZACC = [&]() {
#pragma unroll
    for (int mi = 0; mi < 2; ++mi)
#pragma unroll
      for (int nf = 0; nf < 4; ++nf)
#pragma unroll
        for (int q = 0; q < 4; ++q) acc[mi][nf][q] = 0.f;
  };
  auto LDSA = [&](int kk, bf16x8* a) {
#pragma unroll
    for (int mi = 0; mi < 2; ++mi) {
      int row = wrow + mi * 16 + lrow;
      int seg = (kk >> 3) ^ (row & 15);
      a[mi] = *(const bf16x8*)&sEH[row * 128 + seg * 8];
    }
  };
  // one pipelined chunk-step (R10 engine)
  auto STEP = [&](int buf, const short* nextCp, const bf16x8* a) {
    if (nextCp) STAGE(nextCp, buf ^ 1);
    bf16x8 b[4];
#pragma unroll
    for (int nf = 0; nf < 4; ++nf) {
      int row = wcol + nf * 16 + lrow;
      int seg = kgrp ^ ((row >> 1) & 3);
      b[nf] = *(const bf16x8*)&sW[buf][row * 32 + seg * 8];
    }
#pragma unroll
    for (int nf = 0; nf < 4; ++nf)
#pragma unroll
      for (int mi = 0; mi < 2; ++mi)
        acc[mi][nf] = __builtin_amdgcn_mfma_f32_16x16x32_bf16(a[mi], b[nf], acc[mi][nf], 0, 0, 0);
    if (nextCp) asm volatile("s_waitcnt vmcnt(0)" ::: "memory");
    __syncthreads();
  };
  // same step but A gathered inline from hVb (drained by the step's vmcnt(0))
  auto STEPG = [&](int buf, const short* nextCp, const int* r, int c4) {
    bf16x8 a[2];
    const int kk = c4 * 32 + kgrp * 8;
#pragma unroll
    for (int mi = 0; mi < 2; ++mi)
      a[mi] = *(const bf16x8*)(hVb + (size_t)r[mi] * 128 + kk);
    STEP(buf, nextCp, a);
  };

  // ---------------- V phase: Wv chunks 0..3 x sEH(hE) ----------------
  ZACC();
#pragma unroll
  for (int c = 0; c < 4; ++c) {
    bf16x8 a[2];
    LDSA(c * 32 + kgrp * 8, a);
    const short* nxt = (c < 3) ? (Wv + (c + 1) * 4096) : (W1 + 4 * 4096);
    STEP(c & 1, nxt, a);
  }
  // defer V output: pack (acc + bv) to bf16 pairs (16 VGPRs)
  unsigned vpk[2][4][2];
  {
    float bvc[4];
#pragma unroll
    for (int nf = 0; nf < 4; ++nf) bvc[nf] = bv[wcol + nf * 16 + lrow];
#pragma unroll
    for (int mi = 0; mi < 2; ++mi)
#pragma unroll
      for (int nf = 0; nf < 4; ++nf) {
        vpk[mi][nf][0] = cvtpk(acc[mi][nf][0] + bvc[nf], acc[mi][nf][1] + bvc[nf]);
        vpk[mi][nf][1] = cvtpk(acc[mi][nf][2] + bvc[nf], acc[mi][nf][3] + bvc[nf]);
      }
  }

  // ---------------- layer 1: hE section (W1 c4..c7), aS (c0..c3), aD (c8..c11)
  ZACC();
#pragma unroll
  for (int c = 0; c < 4; ++c) {
    bf16x8 a[2];
    LDSA(c * 32 + kgrp * 8, a);
    const short* nxt = (c < 3) ? (W1 + (5 + c) * 4096) : W1;
    STEP(c & 1, nxt, a);
  }
  STEPG(0, W1 + 1 * 4096, rS, 0);
  STEPG(1, W1 + 2 * 4096, rS, 1);
  STEPG(0, W1 + 3 * 4096, rS, 2);
  STEPG(1, W1 + 8 * 4096, rS, 3);
  STEPG(0, W1 + 9 * 4096, rD, 0);
  STEPG(1, W1 + 10 * 4096, rD, 1);
  STEPG(0, W1 + 11 * 4096, rD, 2);
  STEPG(1, W2, rD, 3);

  // ---- L1 epilogue: sEH = relu(acc + b1) (hE dead after c4..c7) ----
  {
    float b1c[4];
#pragma unroll
    for (int nf = 0; nf < 4; ++nf) b1c[nf] = b1[wcol + nf * 16 + lrow];
#pragma unroll
    for (int mi = 0; mi < 2; ++mi)
#pragma unroll
      for (int nf = 0; nf < 4; ++nf)
#pragma unroll
        for (int q = 0; q < 4; ++q) {
          int row = wrow + mi * 16 + kgrp * 4 + q;
          int col = wcol + nf * 16 + lrow;
          int seg = (col >> 3) ^ (row & 15);
          sEH[row * 128 + seg * 8 + (col & 7)] =
              f2bf1(fmaxf(acc[mi][nf][q] + b1c[nf], 0.f));
        }
  }
  __syncthreads();

  // ---------------- layer 2: W2 chunks 0..3 x sEH(H) ----------------
  ZACC();
#pragma unroll
  for (int c = 0; c < 4; ++c) {
    bf16x8 a[2];
    LDSA(c * 32 + kgrp * 8, a);
    const short* nxt = (c < 3) ? (W2 + (c + 1) * 4096) : nullptr;
    STEP(c & 1, nxt, a);
  }
  // ---- L2 epilogue (+ folded layer 3) ----
  {
    float b2c[4], w3v[4][4];
#pragma unroll
    for (int nf = 0; nf < 4; ++nf) {
      int col = wcol + nf * 16 + lrow;
      b2c[nf] = b2[col];
#pragma unroll
      for (int h = 0; h < 4; ++h) w3v[h][nf] = bf2f((u16)W3b[h * 128 + col]);
    }
#pragma unroll
    for (int mi = 0; mi < 2; ++mi)
#pragma unroll
      for (int q = 0; q < 4; ++q) {
        float p0 = 0.f, p1 = 0.f, p2 = 0.f, p3 = 0.f;
#pragma unroll
        for (int nf = 0; nf < 4; ++nf) {
          float x = fmaxf(acc[mi][nf][q] + b2c[nf], 0.f);
          p0 += x * w3v[0][nf]; p1 += x * w3v[1][nf];
          p2 += x * w3v[2][nf]; p3 += x * w3v[3][nf];
        }
#pragma unroll
        for (int o = 1; o < 16; o <<= 1) {
          p0 += __shfl_xor(p0, o); p1 += __shfl_xor(p1, o);
          p2 += __shfl_xor(p2, o); p3 += __shfl_xor(p3, o);
        }
        if (lrow < 4) {
          float pw = (lrow == 0) ? p0 : (lrow == 1) ? p1 : (lrow == 2) ? p2 : p3;
          sPart[wrow + mi * 16 + kgrp * 4 + q][lrow][wid & 1] = pw;
        }
      }
  }
  __syncthreads();
  if (t < 64) {
    int e = eBase + t;
    if (e < E) {
      float4 lg;
      lg.x = (sPart[t][0][0] + sPart[t][0][1] + b3[0]) * 0.17677669529663687f;
      lg.y = (sPart[t][1][0] + sPart[t][1][1] + b3[1]) * 0.17677669529663687f;
      lg.z = (sPart[t][2][0] + sPart[t][2][1] + b3[2]) * 0.17677669529663687f;
      lg.w = (sPart[t][3][0] + sPart[t][3][1] + b3[3]) * 0.17677669529663687f;
      *(float4*)(logits + (size_t)e * 4) = lg;
    }
  }

  // ---------------- V finale: gelu(vpk) -> sEH (dead) -> coalesced store ----
#pragma unroll
  for (int mi = 0; mi < 2; ++mi)
#pragma unroll
    for (int nf = 0; nf < 4; ++nf)
#pragma unroll
      for (int p = 0; p < 2; ++p) {
        float x0 = bfu_lo(vpk[mi][nf][p]);
        float x1 = bfu_hi(vpk[mi][nf][p]);
        int col = wcol + nf * 16 + lrow;
        int row0 = wrow + mi * 16 + kgrp * 4 + p * 2;
        int seg0 = (col >> 3) ^ (row0 & 15);
        int seg1 = (col >> 3) ^ ((row0 + 1) & 15);
        sEH[row0 * 128 + seg0 * 8 + (col & 7)] = f2bf1(gelu1(x0));
        sEH[(row0 + 1) * 128 + seg1 * 8 + (col & 7)] = f2bf1(gelu1(x1));
      }
  __syncthreads();
#pragma unroll
  for (int i = 0; i < 4; ++i) {
    int u = t + i * 256;             // 0..1023 16B-lines
    int row = u >> 4, g16 = u & 15;
    int seg = g16 ^ (row & 15);
    uint4 v = *(const uint4*)&sEH[row * 128 + seg * 8];
    int e = eBase + row;
    if (e < E) *(uint4*)(Vout + (size_t)e * 128 + g16 * 8) = v;
  }
}

// ---------------- node kernels (order-indirected) ----------------
__global__ void __launch_bounds__(256)
nm_kernel(const float* __restrict__ logits, const int* __restrict__ offs,
          const int* __restrict__ order, float* __restrict__ attw,
          float* __restrict__ inv, int nN) {
  const int wid = threadIdx.x >> 6, lane = threadIdx.x & 63;
  const int nW = gridDim.x * 4;
  for (int v = blockIdx.x * 4 + wid; v < nN; v += nW) {
    const int base = offs[v];
    const int deg = offs[v + 1] - base;
    float m0 = -3e38f, m1 = -3e38f, m2 = -3e38f, m3 = -3e38f;
    for (int i = lane; i < deg; i += 64) {
      int e = order[base + i];
      float4 l = *(const float4*)(logits + (size_t)e * 4);
      m0 = fmaxf(m0, l.x); m1 = fmaxf(m1, l.y);
      m2 = fmaxf(m2, l.z); m3 = fmaxf(m3, l.w);
    }
#pragma unroll
    for (int o = 32; o > 0; o >>= 1) {
      m0 = fmaxf(m0, __shfl_xor(m0, o)); m1 = fmaxf(m1, __shfl_xor(m1, o));
      m2 = fmaxf(m2, __shfl_xor(m2, o)); m3 = fmaxf(m3, __shfl_xor(m3, o));
    }
    float d0 = 0.f, d1 = 0.f, d2 = 0.f, d3 = 0.f;
    for (int i = lane; i < deg; i += 64) {
      int e = order[base + i];
      float4 l = *(const float4*)(logits + (size_t)e * 4);
      float4 ex;
      ex.x = __expf(l.x - m0); ex.y = __expf(l.y - m1);
      ex.z = __expf(l.z - m2); ex.w = __expf(l.w - m3);
      *(float4*)(attw + (size_t)e * 4) = ex;
      d0 += ex.x; d1 += ex.y; d2 += ex.z; d3 += ex.w;
    }
#pragma unroll
    for (int o = 32; o > 0; o >>= 1) {
      d0 += __shfl_xor(d0, o); d1 += __shfl_xor(d1, o);
      d2 += __shfl_xor(d2, o); d3 += __shfl_xor(d3, o);
    }
    if (lane < 4) {
      float dv = (lane == 0) ? d0 : (lane == 1) ? d1 : (lane == 2) ? d2 : d3;
      inv[(size_t)v * 4 + lane] = (dv > 0.f) ? 1.f / dv : 0.f;
    }
  }
}

__device__ __forceinline__ float dot8(const float* ag, uint4 w) {
  unsigned wr[4] = {w.x, w.y, w.z, w.w};
  float s = 0.f;
#pragma unroll
  for (int q = 0; q < 4; ++q) {
    s += ag[2 * q]     * bf2f((u16)(wr[q] & 0xffffu));
    s += ag[2 * q + 1] * bf2f((u16)(wr[q] >> 16));
  }
  return s;
}

// one node per WAVE; lane = 16 dim-groups x 4 edge-slots (16B V loads);
// Wo/Wg cached in LDS (XOR-swizzled); grid-stride over nodes.
__global__ void __launch_bounds__(256, 2)
agg_kernel(const float* __restrict__ hV, const float* __restrict__ attw,
           const float* __restrict__ inv, const u16* __restrict__ V,
           const int* __restrict__ offs, const int* __restrict__ order,
           const short* __restrict__ Wob, const short* __restrict__ Wgb,
           const float* __restrict__ gb, float* __restrict__ out, int nN) {
  __shared__ u16 sW[2][16384];      // 64KB
  __shared__ float sAgg[4][132];
  const int t = threadIdx.x;
#pragma unroll
  for (int i = 0; i < 8; ++i) {
    int idx = t + i * 256;          // 0..2047 uint4 per matrix
    int row = idx >> 4, k16 = idx & 15;
    int di = row * 128 + ((k16 ^ (row & 15)) * 8);
    *(uint4*)&sW[0][di] = ((const uint4*)Wob)[idx];
    *(uint4*)&sW[1][di] = ((const uint4*)Wgb)[idx];
  }
  __syncthreads();
  const int wid = t >> 6, lane = t & 63;
  const int dgrp = lane & 15, egrp = lane >> 4, h = dgrp >> 2;
  const int j0 = lane, j1 = lane + 64;
  const int s0 = (j0 & 15), s1 = (j1 & 15);
  for (int v = blockIdx.x * 4 + wid; v < nN; v += gridDim.x * 4) {
    const int base = offs[v], deg = offs[v + 1] - base;
    float a[8];
#pragma unroll
    for (int q = 0; q < 8; ++q) a[q] = 0.f;
    for (int i = egrp; i < deg; i += 4) {
      int e = order[base + i];
      float w = attw[(size_t)e * 4 + h];
      bf16x8 vv = *(const bf16x8*)(V + (size_t)e * 128 + dgrp * 8);
#pragma unroll
      for (int q = 0; q < 8; ++q) a[q] += w * bf2f((u16)vv[q]);
    }
#pragma unroll
    for (int q = 0; q < 8; ++q) {
      a[q] += __shfl_xor(a[q], 16);
      a[q] += __shfl_xor(a[q], 32);
    }
    if (egrp == 0) {
      float innv = inv[(size_t)v * 4 + h];
#pragma unroll
      for (int q = 0; q < 8; ++q) sAgg[wid][dgrp * 8 + q] = a[q] * innv;
    }
    asm volatile("s_waitcnt lgkmcnt(0)" ::: "memory");
    __builtin_amdgcn_wave_barrier();
    float o0 = 0.f, o1 = 0.f, g0 = 0.f, g1 = 0.f;
#pragma unroll 4
    for (int k = 0; k < 128; k += 8) {
      float a8[8];
#pragma unroll
      for (int q = 0; q < 8; ++q) a8[q] = sAgg[wid][k + q];
      int k16 = k >> 3;
      uint4 wo0 = *(const uint4*)&sW[0][j0 * 128 + ((k16 ^ s0) * 8)];
      uint4 wo1 = *(const uint4*)&sW[0][j1 * 128 + ((k16 ^ s1) * 8)];
      uint4 wg0 = *(const uint4*)&sW[1][j0 * 128 + ((k16 ^ s0) * 8)];
      uint4 wg1 = *(const uint4*)&sW[1][j1 * 128 + ((k16 ^ s1) * 8)];
      o0 += dot8(a8, wo0); o1 += dot8(a8, wo1);
      g0 += dot8(a8, wg0); g1 += dot8(a8, wg1);
    }
    float gg0 = 1.f / (1.f + __expf(-(g0 + gb[j0])));
    float gg1 = 1.f / (1.f + __expf(-(g1 + gb[j1])));
    out[(size_t)v * 128 + j0] = hV[(size_t)v * 128 + j0] + o0 * gg0;
    out[(size_t)v * 128 + j1] = hV[(size_t)v * 128 + j1] + o1 * gg1;
    asm volatile("s_waitcnt lgkmcnt(0)" ::: "memory");
    __builtin_amdgcn_wave_barrier();
  }
}

// ---------------- fallback (ws too small marker) ----------------
__global__ void fb_kernel(const float* __restrict__ hV, float* __restrict__ out, int n) {
  int i = blockIdx.x * 256 + threadIdx.x;
  if (i < n) out[i] = hV[i] + 0.5f;
}

extern "C" void kernel_launch(void* const* d_in, const int* in_sizes, int n_in,
                              void* d_out, int out_size, void* d_ws, size_t ws_size,
                              hipStream_t stream) {
  const float* hV   = (const float*)d_in[0];
  const float* hE   = (const float*)d_in[1];
  const void*  eidx = d_in[2];
  const float* WvW  = (const float*)d_in[3];
  const float* WvB  = (const float*)d_in[4];
  const float* B1w  = (const float*)d_in[5];
  const float* B1b  = (const float*)d_in[6];
  const float* B2w  = (const float*)d_in[7];
  const float* B2b  = (const float*)d_in[8];
  const float* B3w  = (const float*)d_in[9];
  const float* B3b  = (const float*)d_in[10];
  const float* WoW  = (const float*)d_in[11];
  const float* GW   = (const float*)d_in[12];
  const float* GB   = (const float*)d_in[13];

  const int Nn = in_sizes[0] / 128;
  const int E  = in_sizes[1] / 128;
  if (Nn <= 0 || E <= 0) return;

  char* ws = (char*)d_ws;
  size_t off = 0;
  auto alloc = [&](size_t b) { size_t o = off; off += (b + 255) & ~(size_t)255; return o; };
  const size_t o_idx   = alloc((size_t)2 * E * 4);
  const size_t o_cnt   = alloc((size_t)(Nn + 1) * 4);
  const size_t o_offs  = alloc((size_t)(Nn + 1) * 4);
  const size_t o_cur   = alloc((size_t)Nn * 4);
  const size_t o_order = alloc((size_t)E * 4);
  const size_t o_flag  = alloc(256);
  const size_t o_log   = alloc((size_t)E * 16);
  const size_t o_attw  = alloc((size_t)E * 16);
  const size_t o_inv   = alloc((size_t)Nn * 16);
  const size_t o_V     = alloc((size_t)E * 256);
  const size_t o_hVb   = alloc((size_t)Nn * 256);
  const size_t o_wbf   = alloc((size_t)115200 * 2);

  if (off > ws_size) {
    fb_kernel<<<(out_size + 255) / 256, 256, 0, stream>>>(hV, (float*)d_out, out_size);
    return;
  }

  int*   idx32  = (int*)(ws + o_idx);
  int*   cnt    = (int*)(ws + o_cnt);
  int*   offsP  = (int*)(ws + o_offs);
  int*   cur    = (int*)(ws + o_cur);
  int*   order  = (int*)(ws + o_order);
  int*   flag   = (int*)(ws + o_flag);
  float* logits = (float*)(ws + o_log);
  float* attw   = (float*)(ws + o_attw);
  float* invd   = (float*)(ws + o_inv);
  u16*   Vb     = (u16*)(ws + o_V);
  u16*   hVb    = (u16*)(ws + o_hVb);
  short* wbf    = (short*)(ws + o_wbf);

  short* W1b = wbf;
  short* W2b = wbf + 49152;
  short* W3b = wbf + 65536;
  short* Wvb = wbf + 66048;
  short* Wob = wbf + 82432;
  short* Wgb = wbf + 98816;

  const int* src = idx32;
  const int* dst = idx32 + E;

  detect_kernel<<<1, 256, 0, stream>>>((const unsigned*)eidx, flag);
  hipMemsetAsync(cnt, 0, (size_t)(Nn + 1) * 4, stream);
  hipMemsetAsync(cur, 0, (size_t)Nn * 4, stream);
  convert_count_kernel<<<(2 * E + 255) / 256, 256, 0, stream>>>(eidx, idx32, flag, cnt, E);
  scan_kernel<<<1, 1024, 0, stream>>>(cnt, offsP, Nn);
  scatter_kernel<<<(E + 255) / 256, 256, 0, stream>>>(src, offsP, cur, order, E);
  wcvt_kernel<<<(115200 + 255) / 256, 256, 0, stream>>>(B1w, B2w, B3w, WvW, WoW, GW, wbf);
  cvtbf_kernel<<<512, 256, 0, stream>>>(hV, hVb, (long)Nn * 16);

  edge_kernel<<<(E + 63) / 64, 256, 0, stream>>>(
      hVb, hE, src, dst, Vb, W1b, B1b, W2b, B2b, W3b, B3b, Wvb, WvB, logits, E);

  nm_kernel<<<2048, 256, 0, stream>>>(logits, offsP, order, attw, invd, Nn);

  agg_kernel<<<512, 256, 0, stream>>>(
      hV, attw, invd, Vb, offsP, order, Wob, Wgb, GB, (float*)d_out, Nn);
}